// Round 7
// baseline (236.902 us; speedup 1.0000x reference)
//
#include <hip/hip_runtime.h>
#include <math.h>

typedef __attribute__((ext_vector_type(4))) float f32x4;
typedef __attribute__((ext_vector_type(8))) short s16x8;

__device__ inline unsigned f2bf(float f) {
    unsigned u = __float_as_uint(f);
    u += 0x7FFFu + ((u >> 16) & 1u);
    return u >> 16;
}
__device__ inline float bflo(unsigned u) { return __uint_as_float(u << 16); }
__device__ inline float bfhi(unsigned u) { return __uint_as_float(u & 0xFFFF0000u); }

// ---------------------------------------------------------------------------
// pack_all: blocks 0..511 -> x (2,256,8,32,32) f32 to xt[n][y][x][c] bf16;
//           blocks 512..  -> weight to Wp[t][o][c], offset_w to Wo[t][m32][c].
// (code paths identical to r3's pack_x/pack_wo; merged form data-proven in r5)
// ---------------------------------------------------------------------------
__global__ __launch_bounds__(256) void pack_all(
    const float* __restrict__ x, const float* __restrict__ w,
    const float* __restrict__ ow, unsigned* __restrict__ xt32,
    short* __restrict__ Wp, short* __restrict__ Wo)
{
    const int tid = threadIdx.x;
    if (blockIdx.x < 512) {
        __shared__ float tile[256][33];
        const int n = blockIdx.x >> 5, y = blockIdx.x & 31;
        const int b = n >> 3, ts = n & 7;
        const float* src = x + (((size_t)b * 256 * 8) + ts) * 1024 + y * 32;
        #pragma unroll
        for (int rep = 0; rep < 32; ++rep) {
            int c = rep * 8 + (tid >> 5), ww = tid & 31;
            tile[c][ww] = src[(size_t)c * 8192 + ww];
        }
        __syncthreads();
        unsigned* dst = xt32 + ((size_t)n * 1024 + y * 32) * 128;
        #pragma unroll
        for (int rep = 0; rep < 16; ++rep) {
            int idx = rep * 256 + tid;
            int cp = idx & 127, ww = idx >> 7;
            unsigned lo = f2bf(tile[2 * cp][ww]);
            unsigned hi = f2bf(tile[2 * cp + 1][ww]);
            dst[(size_t)ww * 128 + cp] = lo | (hi << 16);
        }
    } else {
        int j = (blockIdx.x - 512) * 256 + tid;
        if (j < 9 * 256 * 256) {
            int c = j & 255, o = (j >> 8) & 255, t = j >> 16;
            Wp[j] = (short)f2bf(w[((size_t)o * 256 + c) * 9 + t]);
        } else {
            int k = j - 9 * 256 * 256;              // < 9*32*256
            int c = k & 255, m = (k >> 8) & 31, t = k >> 13;
            float v = 0.f;
            if (m < 27) v = ow[((size_t)m * 256 + c) * 9 + t];
            Wo[k] = (short)f2bf(v);
        }
    }
}

// ---------------------------------------------------------------------------
// offsets_kernel: r3-VERBATIM. MFMA offset-conv + descriptor math -> descW/I.
// ---------------------------------------------------------------------------
__global__ __launch_bounds__(256) void offsets_kernel(
    const short* __restrict__ xt, const short* __restrict__ Wo,
    const float* __restrict__ ob, float4* __restrict__ descW,
    int4* __restrict__ descI)
{
    __shared__ float pom[2][32][33];
    const int tid = threadIdx.x;
    const int n = blockIdx.x >> 5, ho = blockIdx.x & 31;
    const int lane = tid & 63, wv = tid >> 6;
    const int nt = wv & 1, half = wv >> 1;
    const int l15 = lane & 15, quad = lane >> 4;
    const int pos = nt * 16 + l15;
    const short* xn = xt + (size_t)n * (1024 * 256);
    const s16x8 z8 = {0, 0, 0, 0, 0, 0, 0, 0};

    f32x4 oacc0 = {0, 0, 0, 0}, oacc1 = {0, 0, 0, 0};
    for (int t = 0; t < 9; ++t) {
        int ki = t / 3, kj = t - 3 * ki;
        int y = ho - 1 + ki;
        if (y < 0 || y >= 32) continue;
        int xc = pos - 1 + kj;
        bool vx = (xc >= 0) && (xc < 32);
        int xcl = min(max(xc, 0), 31);
        const short* bp  = xn + (y * 32 + xcl) * 256;
        const short* ap0 = Wo + (t * 32 + l15) * 256;
        #pragma unroll
        for (int cc = 0; cc < 4; ++cc) {
            int c = half * 128 + cc * 32 + quad * 8;
            s16x8 bfrag = *(const s16x8*)(bp + c);
            if (!vx) bfrag = z8;
            s16x8 a0 = *(const s16x8*)(ap0 + c);
            s16x8 a1 = *(const s16x8*)(ap0 + 16 * 256 + c);
            oacc0 = __builtin_amdgcn_mfma_f32_16x16x32_bf16(a0, bfrag, oacc0, 0, 0, 0);
            oacc1 = __builtin_amdgcn_mfma_f32_16x16x32_bf16(a1, bfrag, oacc1, 0, 0, 0);
        }
    }
    #pragma unroll
    for (int r = 0; r < 4; ++r) {
        pom[half][quad * 4 + r][pos]      = oacc0[r];
        pom[half][16 + quad * 4 + r][pos] = oacc1[r];
    }
    __syncthreads();

    for (int s = tid; s < 288; s += 256) {
        int t = s >> 5, wo = s & 31;
        float dy = pom[0][2 * t][wo]     + pom[1][2 * t][wo]     + ob[2 * t];
        float dx = pom[0][2 * t + 1][wo] + pom[1][2 * t + 1][wo] + ob[2 * t + 1];
        float mv = pom[0][18 + t][wo]    + pom[1][18 + t][wo]    + ob[18 + t];
        float mk = 1.0f / (1.0f + __expf(-mv));
        float py = dy + (float)(ho - 1 + t / 3);
        float px = dx + (float)(wo - 1 + t % 3);
        float y0f = floorf(py), x0f = floorf(px);
        float ty = py - y0f, tx = px - x0f;
        int y0 = (int)y0f, x0 = (int)x0f;
        int y1 = y0 + 1, x1 = x0 + 1;
        bool vy0 = (y0 >= 0) && (y0 < 32), vy1 = (y1 >= 0) && (y1 < 32);
        bool vx0 = (x0 >= 0) && (x0 < 32), vx1 = (x1 >= 0) && (x1 < 32);
        int cy0 = min(max(y0, 0), 31), cy1 = min(max(y1, 0), 31);
        int cx0 = min(max(x0, 0), 31), cx1 = min(max(x1, 0), 31);
        float b0 = (1.f - ty) * (1.f - tx) * mk * (float)(vy0 && vx0);
        float b1 = (1.f - ty) * tx         * mk * (float)(vy0 && vx1);
        float b2 = ty * (1.f - tx)         * mk * (float)(vy1 && vx0);
        float b3 = ty * tx                 * mk * (float)(vy1 && vx1);
        size_t base = (size_t)(n * 32 + ho) * 288 + s;
        descW[base] = make_float4(b0, b1, b2, b3);
        descI[base] = make_int4((cy0 * 32 + cx0) * 256, (cy0 * 32 + cx1) * 256,
                                (cy1 * 32 + cx0) * 256, (cy1 * 32 + cx1) * 256);
    }
}

// ---------------------------------------------------------------------------
// init_out: r3-VERBATIM. out = bias (f32).
// ---------------------------------------------------------------------------
__global__ __launch_bounds__(256) void init_out(const float* __restrict__ bias,
                                                float4* __restrict__ out)
{
    int i = blockIdx.x * 256 + threadIdx.x;   // < 1048576
    int oc = (i >> 11) & 255;
    float bv = bias[oc];
    out[i] = make_float4(bv, bv, bv, bv);
}

// ---------------------------------------------------------------------------
// dcn_main: r3-VERBATIM stage machinery; ONLY change: K split 2 -> 4
// (kq = bid&3, 9 stages, cbase = kq*64), grid 1024 -> 2048 for 8 blocks/CU.
// ---------------------------------------------------------------------------
__global__ __launch_bounds__(256, 4) void dcn_main(
    const short* __restrict__ xt, const short* __restrict__ Wp,
    const float4* __restrict__ descW, const int4* __restrict__ descI,
    float* __restrict__ out)
{
    __shared__ short  sB[2][32 * 72];    // 32 pos x 64 c (+8 pad)
    __shared__ float4 sdw[288];
    __shared__ int4   sdi[288];

    const int tid = threadIdx.x;
    const int bid = blockIdx.x;
    const int kq = bid & 3;              // K-quarter (was kh = bid&1)
    const int r  = bid >> 2;
    const int n = r >> 5, ho = r & 31;

    {
        const float4* dW = descW + (size_t)(n * 32 + ho) * 288;
        const int4*   dI = descI + (size_t)(n * 32 + ho) * 288;
        for (int i = tid; i < 288; i += 256) { sdw[i] = dW[i]; sdi[i] = dI[i]; }
    }
    __syncthreads();

    const int pos = tid & 31, oct = tid >> 5;      // repack role
    const int oq = tid >> 6;                       // wave = oc-quarter
    const int lane = tid & 63, l15 = lane & 15, quad = lane >> 4;
    const short* xn = xt + (size_t)n * (1024 * 256);

    f32x4 acc[8];
    #pragma unroll
    for (int i = 0; i < 8; ++i) acc[i] = (f32x4){0, 0, 0, 0};

    for (int s = 0; s < 9; ++s) {
        const int t = s;
        const int cbase = kq * 64;

        // ---- cooperative repack: B-tile[32 pos][64 c] -> LDS -------------
        {
            const float4 w4 = sdw[t * 32 + pos];
            const int4   i4 = sdi[t * 32 + pos];
            const int cc = cbase + oct * 8;
            uint4 q0 = *(const uint4*)(xn + i4.x + cc);
            uint4 q1 = *(const uint4*)(xn + i4.y + cc);
            uint4 q2 = *(const uint4*)(xn + i4.z + cc);
            uint4 q3 = *(const uint4*)(xn + i4.w + cc);
            const unsigned* p0 = (const unsigned*)&q0;
            const unsigned* p1 = (const unsigned*)&q1;
            const unsigned* p2 = (const unsigned*)&q2;
            const unsigned* p3 = (const unsigned*)&q3;
            union { s16x8 v; unsigned u[4]; } bu;
            #pragma unroll
            for (int d = 0; d < 4; ++d) {
                float lo = w4.x * bflo(p0[d]) + w4.y * bflo(p1[d])
                         + w4.z * bflo(p2[d]) + w4.w * bflo(p3[d]);
                float hi = w4.x * bfhi(p0[d]) + w4.y * bfhi(p1[d])
                         + w4.z * bfhi(p2[d]) + w4.w * bfhi(p3[d]);
                bu.u[d] = f2bf(lo) | (f2bf(hi) << 16);
            }
            *(s16x8*)&sB[s & 1][pos * 72 + oct * 8] = bu.v;
        }
        __syncthreads();
        // r3-proven single barrier: writes of stage s+2 into buf[s&1] follow
        // barrier(s+1), by which all stage-s reads have drained.

        // ---- A-frags + B-frags + MFMA ------------------------------------
        const short* ap = Wp + ((size_t)(t * 256 + oq * 64 + l15)) * 256
                             + cbase + quad * 8;
        s16x8 afr[4][2];
        #pragma unroll
        for (int mt = 0; mt < 4; ++mt)
            #pragma unroll
            for (int kc = 0; kc < 2; ++kc)
                afr[mt][kc] = *(const s16x8*)(ap + mt * 16 * 256 + kc * 32);

        s16x8 bfr[2][2];
        #pragma unroll
        for (int nt = 0; nt < 2; ++nt)
            #pragma unroll
            for (int kc = 0; kc < 2; ++kc)
                bfr[nt][kc] = *(const s16x8*)
                    &sB[s & 1][(nt * 16 + l15) * 72 + kc * 32 + quad * 8];

        #pragma unroll
        for (int mt = 0; mt < 4; ++mt)
            #pragma unroll
            for (int nt = 0; nt < 2; ++nt) {
                acc[mt * 2 + nt] = __builtin_amdgcn_mfma_f32_16x16x32_bf16(
                    afr[mt][0], bfr[nt][0], acc[mt * 2 + nt], 0, 0, 0);
                acc[mt * 2 + nt] = __builtin_amdgcn_mfma_f32_16x16x32_bf16(
                    afr[mt][1], bfr[nt][1], acc[mt * 2 + nt], 0, 0, 0);
            }
    }

    // ---- epilogue: atomic K-reduce onto bias-initialized out -------------
    const int bb = n >> 3, ts = n & 7;
    #pragma unroll
    for (int mt = 0; mt < 4; ++mt)
        #pragma unroll
        for (int nt = 0; nt < 2; ++nt)
            #pragma unroll
            for (int rr = 0; rr < 4; ++rr) {
                int oc = oq * 64 + mt * 16 + quad * 4 + rr;
                int p  = nt * 16 + l15;
                atomicAdd(out + (((size_t)bb * 256 + oc) * 8 + ts) * 1024
                              + ho * 32 + p,
                          acc[mt * 2 + nt][rr]);
            }
}

// ---------------------------------------------------------------------------
extern "C" void kernel_launch(void* const* d_in, const int* in_sizes, int n_in,
                              void* d_out, int out_size, void* d_ws, size_t ws_size,
                              hipStream_t stream) {
    const float* x        = (const float*)d_in[0];
    const float* weight   = (const float*)d_in[1];
    const float* bias     = (const float*)d_in[2];
    const float* offset_w = (const float*)d_in[3];
    const float* offset_b = (const float*)d_in[4];

    char* ws = (char*)d_ws;
    short*  xt    = (short*)ws;                       ws += (size_t)16 * 1024 * 256 * 2; // 8.39 MB
    short*  Wp    = (short*)ws;                       ws += (size_t)9 * 256 * 256 * 2;   // 1.18 MB
    short*  Wo    = (short*)ws;                       ws += (size_t)9 * 32 * 256 * 2;    // 147 KB
    float4* descW = (float4*)ws;                      ws += (size_t)147456 * 16;         // 2.36 MB
    int4*   descI = (int4*)ws;                        ws += (size_t)147456 * 16;         // 2.36 MB

    pack_all      <<<3104, 256, 0, stream>>>(x, weight, offset_w, (unsigned*)xt, Wp, Wo);
    offsets_kernel<<<512,  256, 0, stream>>>(xt, Wo, offset_b, descW, descI);
    init_out      <<<4096, 256, 0, stream>>>(bias, (float4*)d_out);
    dcn_main      <<<2048, 256, 0, stream>>>(xt, Wp, descW, descI, (float*)d_out);
}

// Round 8
// 229.716 us; speedup vs baseline: 1.0313x; 1.0313x over previous
//
#include <hip/hip_runtime.h>
#include <math.h>

typedef __attribute__((ext_vector_type(4))) float f32x4;
typedef __attribute__((ext_vector_type(8))) short s16x8;

__device__ inline unsigned f2bf(float f) {
    unsigned u = __float_as_uint(f);
    u += 0x7FFFu + ((u >> 16) & 1u);
    return u >> 16;
}
__device__ inline float bflo(unsigned u) { return __uint_as_float(u << 16); }
__device__ inline float bfhi(unsigned u) { return __uint_as_float(u & 0xFFFF0000u); }

// ---------------------------------------------------------------------------
// pack_init: range-dispatched single launch.
//   blocks    0..511  : x (2,256,8,32,32) f32 -> xt[n][y][x][c] bf16 (r3-proven)
//   blocks  512..3103 : weight -> Wp[t][o][c]; offset_w -> Wo[t][m32][c] (r3-proven)
//   blocks 3104..7199 : out = bias broadcast (r3-proven init_out body)
//   blocks 7200..7711 : gpom = 0
// ---------------------------------------------------------------------------
__global__ __launch_bounds__(256) void pack_init(
    const float* __restrict__ x, const float* __restrict__ w,
    const float* __restrict__ ow, const float* __restrict__ bias,
    unsigned* __restrict__ xt32, short* __restrict__ Wp,
    short* __restrict__ Wo, float4* __restrict__ out4,
    float4* __restrict__ gpom4)
{
    const int tid = threadIdx.x;
    const int bid = blockIdx.x;
    if (bid < 512) {
        __shared__ float tile[256][33];
        const int n = bid >> 5, y = bid & 31;
        const int b = n >> 3, ts = n & 7;
        const float* src = x + (((size_t)b * 256 * 8) + ts) * 1024 + y * 32;
        #pragma unroll
        for (int rep = 0; rep < 32; ++rep) {
            int c = rep * 8 + (tid >> 5), ww = tid & 31;
            tile[c][ww] = src[(size_t)c * 8192 + ww];
        }
        __syncthreads();
        unsigned* dst = xt32 + ((size_t)n * 1024 + y * 32) * 128;
        #pragma unroll
        for (int rep = 0; rep < 16; ++rep) {
            int idx = rep * 256 + tid;
            int cp = idx & 127, ww = idx >> 7;
            unsigned lo = f2bf(tile[2 * cp][ww]);
            unsigned hi = f2bf(tile[2 * cp + 1][ww]);
            dst[(size_t)ww * 128 + cp] = lo | (hi << 16);
        }
    } else if (bid < 3104) {
        int j = (bid - 512) * 256 + tid;
        if (j < 9 * 256 * 256) {
            int c = j & 255, o = (j >> 8) & 255, t = j >> 16;
            Wp[j] = (short)f2bf(w[((size_t)o * 256 + c) * 9 + t]);
        } else {
            int k = j - 9 * 256 * 256;              // < 9*32*256
            int c = k & 255, m = (k >> 8) & 31, t = k >> 13;
            float v = 0.f;
            if (m < 27) v = ow[((size_t)m * 256 + c) * 9 + t];
            Wo[k] = (short)f2bf(v);
        }
    } else if (bid < 7200) {
        int i = (bid - 3104) * 256 + tid;           // < 1048576
        int oc = (i >> 11) & 255;
        float bv = bias[oc];
        out4[i] = make_float4(bv, bv, bv, bv);
    } else {
        int i = (bid - 7200) * 256 + tid;           // < 131072
        gpom4[i] = make_float4(0.f, 0.f, 0.f, 0.f);
    }
}

// ---------------------------------------------------------------------------
// conv_part: offset-conv K-partials. Block = (n, ho, kq). 4 waves =
// (nt = wv&1 pos-half, sh = wv>>1 32-ch sub-half of this 64-ch quarter).
// Inner MFMA code is the r2/r3-proven phase-1 body (single cc chunk).
// LDS-reduce over sh, then atomicAdd into gpom[n][ho][row32][wo].
// ---------------------------------------------------------------------------
__global__ __launch_bounds__(256) void conv_part(
    const short* __restrict__ xt, const short* __restrict__ Wo,
    float* __restrict__ gpom)
{
    __shared__ float pom[2][32][33];
    const int tid = threadIdx.x;
    const int bid = blockIdx.x;
    const int kq = bid & 3;
    const int r  = bid >> 2;
    const int n = r >> 5, ho = r & 31;
    const int lane = tid & 63, wv = tid >> 6;
    const int nt = wv & 1, sh = wv >> 1;
    const int l15 = lane & 15, quad = lane >> 4;
    const int pos = nt * 16 + l15;
    const short* xn = xt + (size_t)n * (1024 * 256);
    const s16x8 z8 = {0, 0, 0, 0, 0, 0, 0, 0};

    f32x4 oacc0 = {0, 0, 0, 0}, oacc1 = {0, 0, 0, 0};
    const int c = kq * 64 + sh * 32 + quad * 8;
    for (int t = 0; t < 9; ++t) {
        int ki = t / 3, kj = t - 3 * ki;
        int y = ho - 1 + ki;
        if (y < 0 || y >= 32) continue;              // block-uniform
        int xc = pos - 1 + kj;
        bool vx = (xc >= 0) && (xc < 32);
        int xcl = min(max(xc, 0), 31);
        const short* bp  = xn + (y * 32 + xcl) * 256;
        const short* ap0 = Wo + (t * 32 + l15) * 256;
        s16x8 bfrag = *(const s16x8*)(bp + c);
        if (!vx) bfrag = z8;
        s16x8 a0 = *(const s16x8*)(ap0 + c);
        s16x8 a1 = *(const s16x8*)(ap0 + 16 * 256 + c);
        oacc0 = __builtin_amdgcn_mfma_f32_16x16x32_bf16(a0, bfrag, oacc0, 0, 0, 0);
        oacc1 = __builtin_amdgcn_mfma_f32_16x16x32_bf16(a1, bfrag, oacc1, 0, 0, 0);
    }
    #pragma unroll
    for (int rr = 0; rr < 4; ++rr) {
        pom[sh][quad * 4 + rr][pos]      = oacc0[rr];
        pom[sh][16 + quad * 4 + rr][pos] = oacc1[rr];
    }
    __syncthreads();

    float* gp = gpom + (size_t)(n * 32 + ho) * 1024;
    for (int s = tid; s < 864; s += 256) {          // 27 rows x 32 wo
        int row = s >> 5, wo = s & 31;
        atomicAdd(gp + row * 32 + wo, pom[0][row][wo] + pom[1][row][wo]);
    }
}

// ---------------------------------------------------------------------------
// desc_build: elementwise. One thread per (n,ho,s) descriptor; r1..r3-proven
// bilinear math reading summed gpom.
// ---------------------------------------------------------------------------
__global__ __launch_bounds__(256) void desc_build(
    const float* __restrict__ gpom, const float* __restrict__ ob,
    float4* __restrict__ descW, int4* __restrict__ descI)
{
    int idx = blockIdx.x * 256 + threadIdx.x;       // < 147456
    int p = idx / 288, s = idx - p * 288;
    int ho = p & 31;
    int t = s >> 5, wo = s & 31;
    const float* gp = gpom + (size_t)p * 1024;

    float dy = gp[(2 * t) * 32 + wo]     + ob[2 * t];
    float dx = gp[(2 * t + 1) * 32 + wo] + ob[2 * t + 1];
    float mv = gp[(18 + t) * 32 + wo]    + ob[18 + t];
    float mk = 1.0f / (1.0f + __expf(-mv));
    float py = dy + (float)(ho - 1 + t / 3);
    float px = dx + (float)(wo - 1 + t % 3);
    float y0f = floorf(py), x0f = floorf(px);
    float ty = py - y0f, tx = px - x0f;
    int y0 = (int)y0f, x0 = (int)x0f;
    int y1 = y0 + 1, x1 = x0 + 1;
    bool vy0 = (y0 >= 0) && (y0 < 32), vy1 = (y1 >= 0) && (y1 < 32);
    bool vx0 = (x0 >= 0) && (x0 < 32), vx1 = (x1 >= 0) && (x1 < 32);
    int cy0 = min(max(y0, 0), 31), cy1 = min(max(y1, 0), 31);
    int cx0 = min(max(x0, 0), 31), cx1 = min(max(x1, 0), 31);
    float b0 = (1.f - ty) * (1.f - tx) * mk * (float)(vy0 && vx0);
    float b1 = (1.f - ty) * tx         * mk * (float)(vy0 && vx1);
    float b2 = ty * (1.f - tx)         * mk * (float)(vy1 && vx0);
    float b3 = ty * tx                 * mk * (float)(vy1 && vx1);
    descW[idx] = make_float4(b0, b1, b2, b3);
    descI[idx] = make_int4((cy0 * 32 + cx0) * 256, (cy0 * 32 + cx1) * 256,
                           (cy1 * 32 + cx0) * 256, (cy1 * 32 + cx1) * 256);
}

// ---------------------------------------------------------------------------
// dcn_main: r3-VERBATIM (K-split 2, grid 1024 — the proven 122 us config).
// ---------------------------------------------------------------------------
__global__ __launch_bounds__(256, 4) void dcn_main(
    const short* __restrict__ xt, const short* __restrict__ Wp,
    const float4* __restrict__ descW, const int4* __restrict__ descI,
    float* __restrict__ out)
{
    __shared__ short  sB[2][32 * 72];    // 32 pos x 64 c (+8 pad)
    __shared__ float4 sdw[288];
    __shared__ int4   sdi[288];

    const int tid = threadIdx.x;
    const int bid = blockIdx.x;
    const int kh = bid & 1;
    const int r  = bid >> 1;
    const int n = r >> 5, ho = r & 31;

    {
        const float4* dW = descW + (size_t)(n * 32 + ho) * 288;
        const int4*   dI = descI + (size_t)(n * 32 + ho) * 288;
        for (int i = tid; i < 288; i += 256) { sdw[i] = dW[i]; sdi[i] = dI[i]; }
    }
    __syncthreads();

    const int pos = tid & 31, oct = tid >> 5;      // repack role
    const int oq = tid >> 6;                       // wave = oc-quarter
    const int lane = tid & 63, l15 = lane & 15, quad = lane >> 4;
    const short* xn = xt + (size_t)n * (1024 * 256);

    f32x4 acc[8];
    #pragma unroll
    for (int i = 0; i < 8; ++i) acc[i] = (f32x4){0, 0, 0, 0};

    for (int s = 0; s < 18; ++s) {
        const int t = s % 9;
        const int cbase = (kh * 2 + (s / 9)) * 64;

        // ---- cooperative repack: B-tile[32 pos][64 c] -> LDS -------------
        {
            const float4 w4 = sdw[t * 32 + pos];
            const int4   i4 = sdi[t * 32 + pos];
            const int cc = cbase + oct * 8;
            uint4 q0 = *(const uint4*)(xn + i4.x + cc);
            uint4 q1 = *(const uint4*)(xn + i4.y + cc);
            uint4 q2 = *(const uint4*)(xn + i4.z + cc);
            uint4 q3 = *(const uint4*)(xn + i4.w + cc);
            const unsigned* p0 = (const unsigned*)&q0;
            const unsigned* p1 = (const unsigned*)&q1;
            const unsigned* p2 = (const unsigned*)&q2;
            const unsigned* p3 = (const unsigned*)&q3;
            union { s16x8 v; unsigned u[4]; } bu;
            #pragma unroll
            for (int d = 0; d < 4; ++d) {
                float lo = w4.x * bflo(p0[d]) + w4.y * bflo(p1[d])
                         + w4.z * bflo(p2[d]) + w4.w * bflo(p3[d]);
                float hi = w4.x * bfhi(p0[d]) + w4.y * bfhi(p1[d])
                         + w4.z * bfhi(p2[d]) + w4.w * bfhi(p3[d]);
                bu.u[d] = f2bf(lo) | (f2bf(hi) << 16);
            }
            *(s16x8*)&sB[s & 1][pos * 72 + oct * 8] = bu.v;
        }
        __syncthreads();
        // r3-proven single barrier: writes of stage s+2 into buf[s&1] follow
        // barrier(s+1), by which all stage-s reads have drained.

        // ---- A-frags + B-frags + MFMA ------------------------------------
        const short* ap = Wp + ((size_t)(t * 256 + oq * 64 + l15)) * 256
                             + cbase + quad * 8;
        s16x8 afr[4][2];
        #pragma unroll
        for (int mt = 0; mt < 4; ++mt)
            #pragma unroll
            for (int kc = 0; kc < 2; ++kc)
                afr[mt][kc] = *(const s16x8*)(ap + mt * 16 * 256 + kc * 32);

        s16x8 bfr[2][2];
        #pragma unroll
        for (int nt = 0; nt < 2; ++nt)
            #pragma unroll
            for (int kc = 0; kc < 2; ++kc)
                bfr[nt][kc] = *(const s16x8*)
                    &sB[s & 1][(nt * 16 + l15) * 72 + kc * 32 + quad * 8];

        #pragma unroll
        for (int mt = 0; mt < 4; ++mt)
            #pragma unroll
            for (int nt = 0; nt < 2; ++nt) {
                acc[mt * 2 + nt] = __builtin_amdgcn_mfma_f32_16x16x32_bf16(
                    afr[mt][0], bfr[nt][0], acc[mt * 2 + nt], 0, 0, 0);
                acc[mt * 2 + nt] = __builtin_amdgcn_mfma_f32_16x16x32_bf16(
                    afr[mt][1], bfr[nt][1], acc[mt * 2 + nt], 0, 0, 0);
            }
    }

    // ---- epilogue: atomic K-reduce onto bias-initialized out -------------
    const int bb = n >> 3, ts = n & 7;
    #pragma unroll
    for (int mt = 0; mt < 4; ++mt)
        #pragma unroll
        for (int nt = 0; nt < 2; ++nt)
            #pragma unroll
            for (int rr = 0; rr < 4; ++rr) {
                int oc = oq * 64 + mt * 16 + quad * 4 + rr;
                int p  = nt * 16 + l15;
                atomicAdd(out + (((size_t)bb * 256 + oc) * 8 + ts) * 1024
                              + ho * 32 + p,
                          acc[mt * 2 + nt][rr]);
            }
}

// ---------------------------------------------------------------------------
extern "C" void kernel_launch(void* const* d_in, const int* in_sizes, int n_in,
                              void* d_out, int out_size, void* d_ws, size_t ws_size,
                              hipStream_t stream) {
    const float* x        = (const float*)d_in[0];
    const float* weight   = (const float*)d_in[1];
    const float* bias     = (const float*)d_in[2];
    const float* offset_w = (const float*)d_in[3];
    const float* offset_b = (const float*)d_in[4];

    char* ws = (char*)d_ws;
    short*  xt    = (short*)ws;   ws += (size_t)16 * 1024 * 256 * 2;   // 8.39 MB
    short*  Wp    = (short*)ws;   ws += (size_t)9 * 256 * 256 * 2;     // 1.18 MB
    short*  Wo    = (short*)ws;   ws += (size_t)9 * 32 * 256 * 2;      // 147 KB
    float4* descW = (float4*)ws;  ws += (size_t)147456 * 16;           // 2.36 MB
    int4*   descI = (int4*)ws;    ws += (size_t)147456 * 16;           // 2.36 MB
    float*  gpom  = (float*)ws;   ws += (size_t)16 * 32 * 1024 * 4;    // 2.10 MB

    pack_init<<<7712, 256, 0, stream>>>(x, weight, offset_w, bias,
                                        (unsigned*)xt, Wp, Wo,
                                        (float4*)d_out, (float4*)gpom);
    conv_part <<<2048, 256, 0, stream>>>(xt, Wo, gpom);
    desc_build<<<576,  256, 0, stream>>>(gpom, offset_b, descW, descI);
    dcn_main  <<<1024, 256, 0, stream>>>(xt, Wp, descW, descI, (float*)d_out);
}